// Round 17
// baseline (158.704 us; speedup 1.0000x reference)
//
#include <hip/hip_runtime.h>

// Shapes: B=2, F=T=2048, HIDDEN=1024, HEADS=16, DEPTH=64
#define LOG2E 1.44269504f

typedef __attribute__((ext_vector_type(8))) short short8v;   // 8 bf16
typedef __attribute__((ext_vector_type(4))) float f32x4;
typedef unsigned int u32;
typedef __attribute__((ext_vector_type(4))) u32 u32x4;
typedef __attribute__((address_space(1))) const u32* gp_t;
typedef __attribute__((address_space(3))) u32* lp_t;

#define MFMA(a, b, c) __builtin_amdgcn_mfma_f32_16x16x32_bf16((a), (b), (c), 0, 0, 0)

__device__ __forceinline__ unsigned short f2bf(float f) {  // RNE fp32->bf16
  unsigned int u = __float_as_uint(f);
  u = (u + 0x7fffu + ((u >> 16) & 1u)) >> 16;
  return (unsigned short)u;
}
__device__ __forceinline__ u32 cvtpk(float lo, float hi) {  // HW RNE pack (T12)
  u32 r;
  asm("v_cvt_pk_bf16_f32 %0, %1, %2" : "=v"(r) : "v"(lo), "v"(hi));
  return r;
}

// ------ fused prep: input fp32->bf16 cvt (blocks 0..2047) + weight transpose (2048..6143) ------
__global__ __launch_bounds__(256)
void k_prep(const float* __restrict__ query, const float* __restrict__ source,
            unsigned short* __restrict__ qin_b, unsigned short* __restrict__ src_b,
            const float* __restrict__ w0, const float* __restrict__ w1,
            const float* __restrict__ w2, const float* __restrict__ w3,
            unsigned short* __restrict__ wqkvT, unsigned short* __restrict__ woT) {
  __shared__ float tile[32][33];
  const int bid = blockIdx.x;
  const int tid = threadIdx.x;
  if (bid < 2048) {
    const int n4each = 1048576;
    for (int i = bid * 256 + tid; i < 2 * n4each; i += 2048 * 256) {
      bool second = i >= n4each;
      int j = second ? i - n4each : i;
      float4 v = second ? reinterpret_cast<const float4*>(source)[j]
                        : reinterpret_cast<const float4*>(query)[j];
      ushort4 o;
      o.x = f2bf(v.x); o.y = f2bf(v.y); o.z = f2bf(v.z); o.w = f2bf(v.w);
      (second ? reinterpret_cast<ushort4*>(src_b) : reinterpret_cast<ushort4*>(qin_b))[j] = o;
    }
  } else {
    const int t = bid - 2048;
    const int z = t >> 10, rem = t & 1023;
    const float* in = (z == 0) ? w0 : (z == 1) ? w1 : (z == 2) ? w2 : w3;
    unsigned short* out = (z < 3) ? (wqkvT + (size_t)z * 1048576) : woT;
    const float scale = (z == 0) ? 0.125f * LOG2E : 1.0f;
    const int bx = (rem & 31) * 32, by = (rem >> 5) * 32;
    const int tx = tid & 31, ty = tid >> 5;  // (32,8)
    for (int r = ty; r < 32; r += 8)
      tile[r][tx] = in[(size_t)(by + r) * 1024 + bx + tx];
    __syncthreads();
    for (int r = ty; r < 32; r += 8)
      out[(size_t)(bx + r) * 1024 + by + tx] = f2bf(tile[tx][r] * scale);
  }
}

// ---- bias permute to PACKED BF16 C-fragment layout, *LOG2E ----
// u32 idx ((bid*2 + (tt>>1))*64 + lane)*4 + (tt&1)*2 + rp holds
// cvtpk(bias[fb*16+l15][ch*64+tt*16+g*4+2rp] , ...+2rp+1) * LOG2E; bid = fb*32+ch.
__global__ void k_bias_perm(const float* __restrict__ in, u32* __restrict__ out) {
  int bid = blockIdx.x;  // fb*32 + ch, grid 4096
  int fb = bid >> 5, ch = bid & 31;
  int tid = threadIdx.x;
  int tt = tid >> 6, rem = tid & 63;
  int g = rem >> 4, l15 = rem & 15;
  float4 v = *reinterpret_cast<const float4*>(
      &in[(size_t)(fb * 16 + l15) * 2048 + ch * 64 + tt * 16 + g * 4]);
  uint2 w;
  w.x = cvtpk(v.x * LOG2E, v.y * LOG2E);
  w.y = cvtpk(v.z * LOG2E, v.w * LOG2E);
  *reinterpret_cast<uint2*>(&out[((size_t)(bid * 2 + (tt >> 1)) * 64 + rem) * 4 + (tt & 1) * 2]) = w;
}

// ------------- fused QKV projection GEMM: BM=128, BN=64, BK=64, dbuf (R13-best) -------------
// N=3072 (wq|wk|wv concat). Grid 48x32 = 1536 blocks; 48KB LDS -> 3 blocks/CU resident.
// Q/K blocks (colbase<2048): C^T via MFMA(b,a), quad on h -> uint2 store to [bh][s][64].
// V blocks: MFMA(a,b), quad on s -> uint2 store to V^T [bh][h][2048].
__global__ __launch_bounds__(256)
void k_gemmqkv(const unsigned short* __restrict__ Aq, const unsigned short* __restrict__ Asrc,
               const unsigned short* __restrict__ W,
               unsigned short* __restrict__ dq, unsigned short* __restrict__ dk,
               unsigned short* __restrict__ dv) {
  __shared__ __align__(16) unsigned short Al[2][8192];  // 128 x 64
  __shared__ __align__(16) unsigned short Bl[2][4096];  // 64 x 64
  const int tid = threadIdx.x;
  const int lane = tid & 63, wid = tid >> 6;
  const int g = lane >> 4, l15 = lane & 15, l7 = l15 & 7;
  const int wm = wid >> 1, wn = wid & 1;
  const int rowbase = blockIdx.y * 128;
  const int colbase = blockIdx.x * 64;  // 0..3008
  const bool isV = colbase >= 2048;
  const unsigned short* A = (colbase < 1024) ? Aq : Asrc;
  const int xgl = (g ^ l7) << 4;

  const int jr = tid >> 3;
  const int sc = ((tid & 7) ^ (jr & 7)) << 3;
  const unsigned short* As0 = A + (size_t)(rowbase + jr) * 1024 + sc;
  const unsigned short* Ws0 = W + (size_t)(colbase + jr) * 1024 + sc;

  const f32x4 zf = {0.f, 0.f, 0.f, 0.f};
  f32x4 acc[4][2];
#pragma unroll
  for (int mf = 0; mf < 4; ++mf) { acc[mf][0] = zf; acc[mf][1] = zf; }

  auto stage = [&](int buf, int k0) {
    char* Ad = (char*)&Al[buf][0];
    char* Bd = (char*)&Bl[buf][0];
#pragma unroll
    for (int p = 0; p < 4; ++p)
      __builtin_amdgcn_global_load_lds((gp_t)(As0 + (size_t)p * 32 * 1024 + k0),
                                       (lp_t)(Ad + (p * 256 + tid) * 16), 16, 0, 0);
#pragma unroll
    for (int p = 0; p < 2; ++p)
      __builtin_amdgcn_global_load_lds((gp_t)(Ws0 + (size_t)p * 32 * 1024 + k0),
                                       (lp_t)(Bd + (p * 256 + tid) * 16), 16, 0, 0);
  };
  auto ldfrags = [&](int buf, int kk, short8v af[4], short8v bfr[2]) {
    const char* Ac = (const char*)&Al[buf][0];
    const char* Bc = (const char*)&Bl[buf][0];
#pragma unroll
    for (int mf = 0; mf < 4; ++mf)
      af[mf] = *reinterpret_cast<const short8v*>(
          Ac + ((wm * 64 + mf * 16 + l15) << 7) + (xgl ^ (kk << 6)));
#pragma unroll
    for (int nf = 0; nf < 2; ++nf)
      bfr[nf] = *reinterpret_cast<const short8v*>(
          Bc + ((wn * 32 + nf * 16 + l15) << 7) + (xgl ^ (kk << 6)));
  };

  stage(0, 0);
  __syncthreads();
#pragma unroll 1
  for (int s = 0; s < 16; ++s) {
    if (s < 15) stage((s + 1) & 1, (s + 1) * 64);
    __builtin_amdgcn_s_setprio(1);
    if (!isV) {
#pragma unroll
      for (int kk = 0; kk < 2; ++kk) {
        short8v af[4], bfr[2];
        ldfrags(s & 1, kk, af, bfr);
#pragma unroll
        for (int mf = 0; mf < 4; ++mf)
#pragma unroll
          for (int nf = 0; nf < 2; ++nf) acc[mf][nf] = MFMA(bfr[nf], af[mf], acc[mf][nf]);
      }
    } else {
#pragma unroll
      for (int kk = 0; kk < 2; ++kk) {
        short8v af[4], bfr[2];
        ldfrags(s & 1, kk, af, bfr);
#pragma unroll
        for (int mf = 0; mf < 4; ++mf)
#pragma unroll
          for (int nf = 0; nf < 2; ++nf) acc[mf][nf] = MFMA(af[mf], bfr[nf], acc[mf][nf]);
      }
    }
    __builtin_amdgcn_s_setprio(0);
    __syncthreads();
  }

  if (!isV) {  // C^T: lane row s = l15-based, reg quad = 4 h-cols
    unsigned short* dst = (colbase < 1024) ? dq : dk;
    const int cb = colbase & 1023;
#pragma unroll
    for (int mf = 0; mf < 4; ++mf)
#pragma unroll
      for (int nf = 0; nf < 2; ++nf) {
        f32x4 v = acc[mf][nf];
        int s = rowbase + wm * 64 + mf * 16 + l15;
        int c = cb + wn * 32 + nf * 16 + g * 4;
        int b = s >> 11, s2 = s & 2047, hd = c >> 6, h = c & 63;
        uint2 w; w.x = cvtpk(v[0], v[1]); w.y = cvtpk(v[2], v[3]);
        *reinterpret_cast<uint2*>(dst + ((size_t)(b * 16 + hd) * 2048 + s2) * 64 + h) = w;
      }
  } else {  // C: lane col h = l15-based, reg quad = 4 s-rows -> V^T contiguous in s
    const int cb = colbase - 2048;
#pragma unroll
    for (int mf = 0; mf < 4; ++mf)
#pragma unroll
      for (int nf = 0; nf < 2; ++nf) {
        f32x4 v = acc[mf][nf];
        int s = rowbase + wm * 64 + mf * 16 + g * 4;
        int c = cb + wn * 32 + nf * 16 + l15;
        int b = s >> 11, s2 = s & 2047, hd = c >> 6, h = c & 63;
        uint2 w; w.x = cvtpk(v[0], v[1]); w.y = cvtpk(v[2], v[3]);
        *reinterpret_cast<uint2*>(dv + ((size_t)(b * 16 + hd) * 64 + h) * 2048 + s2) = w;
      }
  }
}

// ------------- out-projection GEMM: BM=128, BN=64, BK=64, dbuf -------------
// C^T via MFMA(b,a); f32x4 store to row-major [4096][1024]. Grid 16x32 = 512 blocks.
__global__ __launch_bounds__(256)
void k_gemmo(const unsigned short* __restrict__ A, const unsigned short* __restrict__ W,
             float* __restrict__ df) {
  __shared__ __align__(16) unsigned short Al[2][8192];  // 128 x 64
  __shared__ __align__(16) unsigned short Bl[2][4096];  // 64 x 64
  const int tid = threadIdx.x;
  const int lane = tid & 63, wid = tid >> 6;
  const int g = lane >> 4, l15 = lane & 15, l7 = l15 & 7;
  const int wm = wid >> 1, wn = wid & 1;
  const int rowbase = blockIdx.y * 128;
  const int colbase = blockIdx.x * 64;
  const int xgl = (g ^ l7) << 4;

  const int jr = tid >> 3;
  const int sc = ((tid & 7) ^ (jr & 7)) << 3;
  const unsigned short* As0 = A + (size_t)(rowbase + jr) * 1024 + sc;
  const unsigned short* Ws0 = W + (size_t)(colbase + jr) * 1024 + sc;

  const f32x4 zf = {0.f, 0.f, 0.f, 0.f};
  f32x4 acc[4][2];
#pragma unroll
  for (int mf = 0; mf < 4; ++mf) { acc[mf][0] = zf; acc[mf][1] = zf; }

  auto stage = [&](int buf, int k0) {
    char* Ad = (char*)&Al[buf][0];
    char* Bd = (char*)&Bl[buf][0];
#pragma unroll
    for (int p = 0; p < 4; ++p)
      __builtin_amdgcn_global_load_lds((gp_t)(As0 + (size_t)p * 32 * 1024 + k0),
                                       (lp_t)(Ad + (p * 256 + tid) * 16), 16, 0, 0);
#pragma unroll
    for (int p = 0; p < 2; ++p)
      __builtin_amdgcn_global_load_lds((gp_t)(Ws0 + (size_t)p * 32 * 1024 + k0),
                                       (lp_t)(Bd + (p * 256 + tid) * 16), 16, 0, 0);
  };

  stage(0, 0);
  __syncthreads();
#pragma unroll 1
  for (int s = 0; s < 16; ++s) {
    if (s < 15) stage((s + 1) & 1, (s + 1) * 64);
    const char* Ac = (const char*)&Al[s & 1][0];
    const char* Bc = (const char*)&Bl[s & 1][0];
    __builtin_amdgcn_s_setprio(1);
#pragma unroll
    for (int kk = 0; kk < 2; ++kk) {
      short8v af[4], bfr[2];
#pragma unroll
      for (int mf = 0; mf < 4; ++mf)
        af[mf] = *reinterpret_cast<const short8v*>(
            Ac + ((wm * 64 + mf * 16 + l15) << 7) + (xgl ^ (kk << 6)));
#pragma unroll
      for (int nf = 0; nf < 2; ++nf)
        bfr[nf] = *reinterpret_cast<const short8v*>(
            Bc + ((wn * 32 + nf * 16 + l15) << 7) + (xgl ^ (kk << 6)));
#pragma unroll
      for (int mf = 0; mf < 4; ++mf)
#pragma unroll
        for (int nf = 0; nf < 2; ++nf) acc[mf][nf] = MFMA(bfr[nf], af[mf], acc[mf][nf]);
    }
    __builtin_amdgcn_s_setprio(0);
    __syncthreads();
  }

#pragma unroll
  for (int mf = 0; mf < 4; ++mf)
#pragma unroll
    for (int nf = 0; nf < 2; ++nf) {
      int s = rowbase + wm * 64 + mf * 16 + l15;
      int c = colbase + wn * 32 + nf * 16 + g * 4;
      *reinterpret_cast<f32x4*>(df + (size_t)s * 1024 + c) = acc[mf][nf];
    }
}

// ---------------- flash attention: two-chunk phases, V direct-from-L2 ----------------
// block = (f-tile 128, one (b,head)); 4 waves x 2 rowgroups x 16 f. Grid 512 (2 blocks/CU).
// V is NOT LDS-staged: per-XCD concurrent K/V working set is ~2MB (ft-major maps
// bn = bid&31 -> bn%8 fixed per XCD) -> V^T fragment loads hit L2 and prefetch into
// VGPRs, removing half the staging VMEM, 16 ds_read_b128 and 8KB LDS writes per phase.
__global__ __launch_bounds__(256, 2)
void k_attn(const unsigned short* __restrict__ qw,    // [B*N][F][64] (* scale * log2e)
            const unsigned short* __restrict__ kw,    // [B*N][T][64]
            const unsigned short* __restrict__ vtw,   // [B*N][64][T]
            const u32* __restrict__ biaspu,           // packed bf16 C-frag layout (* log2e)
            unsigned short* __restrict__ attnb) {     // [B][F][N*64] bf16
  __shared__ __align__(16) unsigned short Kl[2][2][4096];  // [pairbuf][sub][64x64]
  __shared__ __align__(16) unsigned short Pl[4][2048];     // per wave: 2 rg x 16f x 64t

  const int tid = threadIdx.x;
  const int lane = tid & 63, wid = tid >> 6;
  const int g = lane >> 4, l15 = lane & 15, l7 = l15 & 7;
  const int xgl = (g ^ l7) << 4;

  const int bid = blockIdx.x;  // ft-major: 32 consecutive blocks share a bias slab
  const int ft = bid >> 5, bn = bid & 31;
  const int b = bn >> 4, n = bn & 15;

  const size_t hoff = (size_t)bn * (2048 * 64);
  const unsigned short* qp = qw + hoff;
  const unsigned short* kp = kw + hoff;
  const unsigned short* vp = vtw + hoff;

  const int f0 = ft * 128 + wid * 32;   // wave's 32 f-rows (2 rowgroups of 16)
  const int fbb = ft * 8 + wid * 2;     // bias 16-row block index for rg=0

  // K staging sources (pre-swizzled)
  const int jr = tid >> 3;
  const int sc = ((tid & 7) ^ (jr & 7)) << 3;
  const unsigned short* Ks0 = kp + jr * 64 + sc;
  const unsigned short* Ks1 = kp + (jr + 32) * 64 + sc;

  auto stage_pair = [&](int pb, int pi) {  // stages K chunks 2pi, 2pi+1 (4 VMEM/thread)
#pragma unroll
    for (int s = 0; s < 2; ++s) {
      int ci = 2 * pi + s;
      char* Kd = (char*)&Kl[pb][s][0];
      int ko = ci << 12;
      __builtin_amdgcn_global_load_lds((gp_t)(Ks0 + ko), (lp_t)(Kd + tid * 16), 16, 0, 0);
      __builtin_amdgcn_global_load_lds((gp_t)(Ks1 + ko), (lp_t)(Kd + 4096 + tid * 16), 16, 0, 0);
    }
  };

  // V^T direct fragment load (L2-hit): vr[c*4+ht] = V^T[ht*16+l15][ci*64 + c*32 + g*8 ..+8]
  const unsigned short* vlane = vp + (size_t)l15 * 2048 + g * 8;
  auto vload = [&](int ci, short8v vr[8]) {
#pragma unroll
    for (int c = 0; c < 2; ++c)
#pragma unroll
      for (int ht = 0; ht < 4; ++ht)
        vr[c * 4 + ht] = *reinterpret_cast<const short8v*>(
            vlane + (size_t)ht * 16 * 2048 + ci * 64 + c * 32);
  };

  // Q as B-fragment per rowgroup (col f = f0 + rg*16 + l15)
  short8v aq[2][2];
#pragma unroll
  for (int rg = 0; rg < 2; ++rg) {
    aq[rg][0] = *reinterpret_cast<const short8v*>(
        &qp[(size_t)(f0 + rg * 16 + l15) * 64 + g * 8]);
    aq[rg][1] = *reinterpret_cast<const short8v*>(
        &qp[(size_t)(f0 + rg * 16 + l15) * 64 + 32 + g * 8]);
  }

  // bias u32 address: ((fb*32+ci)*2 + tp)*256 + lane*4  (fb = fbb + rg)
  const u32* bias_lane = biaspu + (size_t)fbb * 16384 + lane * 4;

  const f32x4 zf = {0.f, 0.f, 0.f, 0.f};
  f32x4 o[2][4];
#pragma unroll
  for (int rg = 0; rg < 2; ++rg)
#pragma unroll
    for (int ht = 0; ht < 4; ++ht) o[rg][ht] = zf;
  float ls0 = 0.f, ls1 = 0.f;
  char* Pb = (char*)&Pl[wid][0] + l15 * 128;  // rg adds +2048 bytes

  auto bload = [&](int ci, u32x4 bc[2][2]) {  // 4 VMEM (16B) per chunk
#pragma unroll
    for (int rg = 0; rg < 2; ++rg)
#pragma unroll
      for (int tp = 0; tp < 2; ++tp)
        bc[rg][tp] = *reinterpret_cast<const u32x4*>(
            bias_lane + (size_t)rg * 16384 + ci * 512 + tp * 256);
  };

  auto qk = [&](const char* Kc, const u32x4 bc[2][2], f32x4 st[2][4]) {
    __builtin_amdgcn_s_setprio(1);
#pragma unroll
    for (int tt = 0; tt < 4; ++tt) {
      short8v kb0 = *reinterpret_cast<const short8v*>(Kc + ((tt * 16 + l15) << 7) + xgl);
      short8v kb1 = *reinterpret_cast<const short8v*>(Kc + ((tt * 16 + l15) << 7) + (xgl ^ 64));
#pragma unroll
      for (int rg = 0; rg < 2; ++rg) {
        u32 w0 = bc[rg][tt >> 1][(tt & 1) * 2];
        u32 w1 = bc[rg][tt >> 1][(tt & 1) * 2 + 1];
        f32x4 bcr;
        bcr[0] = __uint_as_float(w0 << 16);
        bcr[1] = __uint_as_float(w0 & 0xFFFF0000u);
        bcr[2] = __uint_as_float(w1 << 16);
        bcr[3] = __uint_as_float(w1 & 0xFFFF0000u);
        st[rg][tt] = MFMA(kb1, aq[rg][1], MFMA(kb0, aq[rg][0], bcr));
      }
    }
    __builtin_amdgcn_s_setprio(0);
  };

  auto sm = [&](const f32x4 st[2][4]) {  // fixed-max softmax; P -> LDS
#pragma unroll
    for (int rg = 0; rg < 2; ++rg) {
      float rs = 0.f;
#pragma unroll
      for (int tt = 0; tt < 4; ++tt) {
        float p0 = __builtin_amdgcn_exp2f(st[rg][tt][0]);
        float p1 = __builtin_amdgcn_exp2f(st[rg][tt][1]);
        float p2 = __builtin_amdgcn_exp2f(st[rg][tt][2]);
        float p3 = __builtin_amdgcn_exp2f(st[rg][tt][3]);
        rs += (p0 + p1) + (p2 + p3);
        uint2 w;
        w.x = cvtpk(p0, p1);
        w.y = cvtpk(p2, p3);
        *reinterpret_cast<uint2*>(Pb + rg * 2048 + ((tt * 32 + g * 8) ^ (l7 * 16))) = w;
      }
      rs += __shfl_xor(rs, 16);
      rs += __shfl_xor(rs, 32);
      if (rg == 0) ls0 += rs; else ls1 += rs;
    }
  };

  auto pv = [&](const short8v vr[8]) {
    __builtin_amdgcn_s_setprio(1);
#pragma unroll
    for (int c = 0; c < 2; ++c) {
      short8v pa0 = *reinterpret_cast<const short8v*>(Pb + ((c << 6) ^ xgl));
      short8v pa1 = *reinterpret_cast<const short8v*>(Pb + 2048 + ((c << 6) ^ xgl));
#pragma unroll
      for (int ht = 0; ht < 4; ++ht) {
        o[0][ht] = MFMA(pa0, vr[c * 4 + ht], o[0][ht]);
        o[1][ht] = MFMA(pa1, vr[c * 4 + ht], o[1][ht]);
      }
    }
    __builtin_amdgcn_s_setprio(0);
  };

  u32x4 cbA[2][2], cbB[2][2], nbA[2][2], nbB[2][2];
  short8v vrA[8], vrB[8];
  stage_pair(0, 0);
  bload(0, cbA);
  bload(1, cbB);
  __syncthreads();

#pragma unroll 1
  for (int ph = 0; ph < 16; ++ph) {
    const int pb = ph & 1;
    vload(2 * ph, vrA);          // V chunk A straight to VGPR (L2-hit)
    if (ph < 15) stage_pair(pb ^ 1, ph + 1);
    const char* K0 = (const char*)&Kl[pb][0][0];
    const char* K1 = (const char*)&Kl[pb][1][0];

    f32x4 stA[2][4], stB[2][4];
    qk(K0, cbA, stA);            // MFMA chunk A
    if (ph < 15) bload(2 * ph + 2, nbA);
    qk(K1, cbB, stB);            // MFMA chunk B fills A's latency
    if (ph < 15) bload(2 * ph + 3, nbB);
    sm(stA);                     // VALU + P_A store
    vload(2 * ph + 1, vrB);      // V chunk B prefetch under PV_A
    pv(vrA);                     // MFMA reads P_A + V_A regs
    sm(stB);                     // P_B store
    pv(vrB);                     // MFMA chunk B

    __syncthreads();
#pragma unroll
    for (int rg = 0; rg < 2; ++rg)
#pragma unroll
      for (int q = 0; q < 2; ++q) { cbA[rg][q] = nbA[rg][q]; cbB[rg][q] = nbB[rg][q]; }
  }

#pragma unroll
  for (int rg = 0; rg < 2; ++rg) {
    float inv = 1.f / (rg == 0 ? ls0 : ls1);
    float i0 = __shfl(inv, g * 4 + 0, 16);
    float i1 = __shfl(inv, g * 4 + 1, 16);
    float i2 = __shfl(inv, g * 4 + 2, 16);
    float i3 = __shfl(inv, g * 4 + 3, 16);
#pragma unroll
    for (int ht = 0; ht < 4; ++ht) {
      unsigned short* ob = &attnb[((size_t)b * 2048 + f0 + rg * 16 + g * 4) * 1024 +
                                  n * 64 + ht * 16 + l15];
      ob[0] = f2bf(o[rg][ht][0] * i0);
      ob[1024] = f2bf(o[rg][ht][1] * i1);
      ob[2048] = f2bf(o[rg][ht][2] * i2);
      ob[3072] = f2bf(o[rg][ht][3] * i3);
    }
  }
}

extern "C" void kernel_launch(void* const* d_in, const int* in_sizes, int n_in,
                              void* d_out, int out_size, void* d_ws, size_t ws_size,
                              hipStream_t stream) {
  const float* query  = (const float*)d_in[0];
  const float* source = (const float*)d_in[1];
  const float* bias   = (const float*)d_in[2];
  const float* wq     = (const float*)d_in[3];
  const float* wk     = (const float*)d_in[4];
  const float* wv     = (const float*)d_in[5];
  const float* wo     = (const float*)d_in[6];

  char* ws = (char*)d_ws;
  unsigned short* qin_b  = (unsigned short*)(ws + 0);         // [4096][1024] bf16
  unsigned short* src_b  = (unsigned short*)(ws + 8388608);   // [4096][1024]
  u32*            bias_u = (u32*)(ws + 0);                    // packed bf16 8MB, ALIASES qin
                                                              // (written after QKV GEMM)
  unsigned short* wqkvT  = (unsigned short*)(ws + 16777216);  // [3072][1024] wq|wk|wv
  unsigned short* woT    = (unsigned short*)(ws + 23068672);  // [1024][1024]
  unsigned short* q_ws   = (unsigned short*)(ws + 25165824);  // [32][2048][64]
  unsigned short* k_ws   = (unsigned short*)(ws + 33554432);  // [32][2048][64]
  unsigned short* vT_ws  = (unsigned short*)(ws + 41943040);  // [32][64][2048]
  unsigned short* attn_b = (unsigned short*)(ws + 50331648);  // [4096][1024]

  k_prep<<<6144, 256, 0, stream>>>(query, source, qin_b, src_b,
                                   wq, wk, wv, wo, wqkvT, woT);
  k_gemmqkv<<<dim3(48, 32), 256, 0, stream>>>(qin_b, src_b, wqkvT, q_ws, k_ws, vT_ws);
  k_bias_perm<<<4096, 256, 0, stream>>>(bias, bias_u);  // reuses [0,8MB) after QKV GEMM
  k_attn<<<512, 256, 0, stream>>>(q_ws, k_ws, vT_ws, bias_u, attn_b);
  k_gemmo<<<dim3(16, 32), 256, 0, stream>>>(attn_b, woT, (float*)d_out);
}

// Round 18
// 133.427 us; speedup vs baseline: 1.1894x; 1.1894x over previous
//
#include <hip/hip_runtime.h>

// Shapes: B=2, F=T=2048, HIDDEN=1024, HEADS=16, DEPTH=64
#define LOG2E 1.44269504f

typedef __attribute__((ext_vector_type(8))) short short8v;   // 8 bf16
typedef __attribute__((ext_vector_type(4))) float f32x4;
typedef unsigned int u32;
typedef __attribute__((ext_vector_type(4))) u32 u32x4;
typedef __attribute__((address_space(1))) const u32* gp_t;
typedef __attribute__((address_space(3))) u32* lp_t;

#define MFMA(a, b, c) __builtin_amdgcn_mfma_f32_16x16x32_bf16((a), (b), (c), 0, 0, 0)

__device__ __forceinline__ unsigned short f2bf(float f) {  // RNE fp32->bf16
  unsigned int u = __float_as_uint(f);
  u = (u + 0x7fffu + ((u >> 16) & 1u)) >> 16;
  return (unsigned short)u;
}
__device__ __forceinline__ u32 cvtpk(float lo, float hi) {  // HW RNE pack (T12)
  u32 r;
  asm("v_cvt_pk_bf16_f32 %0, %1, %2" : "=v"(r) : "v"(lo), "v"(hi));
  return r;
}

// ------ fused prep: input fp32->bf16 cvt (blocks 0..2047) + weight transpose (2048..6143) ------
__global__ __launch_bounds__(256)
void k_prep(const float* __restrict__ query, const float* __restrict__ source,
            unsigned short* __restrict__ qin_b, unsigned short* __restrict__ src_b,
            const float* __restrict__ w0, const float* __restrict__ w1,
            const float* __restrict__ w2, const float* __restrict__ w3,
            unsigned short* __restrict__ wqkvT, unsigned short* __restrict__ woT) {
  __shared__ float tile[32][33];
  const int bid = blockIdx.x;
  const int tid = threadIdx.x;
  if (bid < 2048) {
    const int n4each = 1048576;
    for (int i = bid * 256 + tid; i < 2 * n4each; i += 2048 * 256) {
      bool second = i >= n4each;
      int j = second ? i - n4each : i;
      float4 v = second ? reinterpret_cast<const float4*>(source)[j]
                        : reinterpret_cast<const float4*>(query)[j];
      ushort4 o;
      o.x = f2bf(v.x); o.y = f2bf(v.y); o.z = f2bf(v.z); o.w = f2bf(v.w);
      (second ? reinterpret_cast<ushort4*>(src_b) : reinterpret_cast<ushort4*>(qin_b))[j] = o;
    }
  } else {
    const int t = bid - 2048;
    const int z = t >> 10, rem = t & 1023;
    const float* in = (z == 0) ? w0 : (z == 1) ? w1 : (z == 2) ? w2 : w3;
    unsigned short* out = (z < 3) ? (wqkvT + (size_t)z * 1048576) : woT;
    const float scale = (z == 0) ? 0.125f * LOG2E : 1.0f;
    const int bx = (rem & 31) * 32, by = (rem >> 5) * 32;
    const int tx = tid & 31, ty = tid >> 5;  // (32,8)
    for (int r = ty; r < 32; r += 8)
      tile[r][tx] = in[(size_t)(by + r) * 1024 + bx + tx];
    __syncthreads();
    for (int r = ty; r < 32; r += 8)
      out[(size_t)(bx + r) * 1024 + by + tx] = f2bf(tile[tx][r] * scale);
  }
}

// ---- bias permute to PACKED BF16 C-fragment layout, *LOG2E ----
// u32 idx ((bid*2 + (tt>>1))*64 + lane)*4 + (tt&1)*2 + rp holds
// cvtpk(bias[fb*16+l15][ch*64+tt*16+g*4+2rp] , ...+2rp+1) * LOG2E; bid = fb*32+ch.
__global__ void k_bias_perm(const float* __restrict__ in, u32* __restrict__ out) {
  int bid = blockIdx.x;  // fb*32 + ch, grid 4096
  int fb = bid >> 5, ch = bid & 31;
  int tid = threadIdx.x;
  int tt = tid >> 6, rem = tid & 63;
  int g = rem >> 4, l15 = rem & 15;
  float4 v = *reinterpret_cast<const float4*>(
      &in[(size_t)(fb * 16 + l15) * 2048 + ch * 64 + tt * 16 + g * 4]);
  uint2 w;
  w.x = cvtpk(v.x * LOG2E, v.y * LOG2E);
  w.y = cvtpk(v.z * LOG2E, v.w * LOG2E);
  *reinterpret_cast<uint2*>(&out[((size_t)(bid * 2 + (tt >> 1)) * 64 + rem) * 4 + (tt & 1) * 2]) = w;
}

// ------------- fused QKV projection GEMM: BM=128, BN=64, BK=64, dbuf (R13-best) -------------
// N=3072 (wq|wk|wv concat). Grid 48x32 = 1536 blocks; 48KB LDS -> 3 blocks/CU resident.
// Q/K blocks (colbase<2048): C^T via MFMA(b,a), quad on h -> uint2 store to [bh][s][64].
// V blocks: MFMA(a,b), quad on s -> uint2 store to V^T [bh][h][2048].
__global__ __launch_bounds__(256)
void k_gemmqkv(const unsigned short* __restrict__ Aq, const unsigned short* __restrict__ Asrc,
               const unsigned short* __restrict__ W,
               unsigned short* __restrict__ dq, unsigned short* __restrict__ dk,
               unsigned short* __restrict__ dv) {
  __shared__ __align__(16) unsigned short Al[2][8192];  // 128 x 64
  __shared__ __align__(16) unsigned short Bl[2][4096];  // 64 x 64
  const int tid = threadIdx.x;
  const int lane = tid & 63, wid = tid >> 6;
  const int g = lane >> 4, l15 = lane & 15, l7 = l15 & 7;
  const int wm = wid >> 1, wn = wid & 1;
  const int rowbase = blockIdx.y * 128;
  const int colbase = blockIdx.x * 64;  // 0..3008
  const bool isV = colbase >= 2048;
  const unsigned short* A = (colbase < 1024) ? Aq : Asrc;
  const int xgl = (g ^ l7) << 4;

  const int jr = tid >> 3;
  const int sc = ((tid & 7) ^ (jr & 7)) << 3;
  const unsigned short* As0 = A + (size_t)(rowbase + jr) * 1024 + sc;
  const unsigned short* Ws0 = W + (size_t)(colbase + jr) * 1024 + sc;

  const f32x4 zf = {0.f, 0.f, 0.f, 0.f};
  f32x4 acc[4][2];
#pragma unroll
  for (int mf = 0; mf < 4; ++mf) { acc[mf][0] = zf; acc[mf][1] = zf; }

  auto stage = [&](int buf, int k0) {
    char* Ad = (char*)&Al[buf][0];
    char* Bd = (char*)&Bl[buf][0];
#pragma unroll
    for (int p = 0; p < 4; ++p)
      __builtin_amdgcn_global_load_lds((gp_t)(As0 + (size_t)p * 32 * 1024 + k0),
                                       (lp_t)(Ad + (p * 256 + tid) * 16), 16, 0, 0);
#pragma unroll
    for (int p = 0; p < 2; ++p)
      __builtin_amdgcn_global_load_lds((gp_t)(Ws0 + (size_t)p * 32 * 1024 + k0),
                                       (lp_t)(Bd + (p * 256 + tid) * 16), 16, 0, 0);
  };
  auto ldfrags = [&](int buf, int kk, short8v af[4], short8v bfr[2]) {
    const char* Ac = (const char*)&Al[buf][0];
    const char* Bc = (const char*)&Bl[buf][0];
#pragma unroll
    for (int mf = 0; mf < 4; ++mf)
      af[mf] = *reinterpret_cast<const short8v*>(
          Ac + ((wm * 64 + mf * 16 + l15) << 7) + (xgl ^ (kk << 6)));
#pragma unroll
    for (int nf = 0; nf < 2; ++nf)
      bfr[nf] = *reinterpret_cast<const short8v*>(
          Bc + ((wn * 32 + nf * 16 + l15) << 7) + (xgl ^ (kk << 6)));
  };

  stage(0, 0);
  __syncthreads();
#pragma unroll 1
  for (int s = 0; s < 16; ++s) {
    if (s < 15) stage((s + 1) & 1, (s + 1) * 64);
    __builtin_amdgcn_s_setprio(1);
    if (!isV) {
#pragma unroll
      for (int kk = 0; kk < 2; ++kk) {
        short8v af[4], bfr[2];
        ldfrags(s & 1, kk, af, bfr);
#pragma unroll
        for (int mf = 0; mf < 4; ++mf)
#pragma unroll
          for (int nf = 0; nf < 2; ++nf) acc[mf][nf] = MFMA(bfr[nf], af[mf], acc[mf][nf]);
      }
    } else {
#pragma unroll
      for (int kk = 0; kk < 2; ++kk) {
        short8v af[4], bfr[2];
        ldfrags(s & 1, kk, af, bfr);
#pragma unroll
        for (int mf = 0; mf < 4; ++mf)
#pragma unroll
          for (int nf = 0; nf < 2; ++nf) acc[mf][nf] = MFMA(af[mf], bfr[nf], acc[mf][nf]);
      }
    }
    __builtin_amdgcn_s_setprio(0);
    __syncthreads();
  }

  if (!isV) {  // C^T: lane row s = l15-based, reg quad = 4 h-cols
    unsigned short* dst = (colbase < 1024) ? dq : dk;
    const int cb = colbase & 1023;
#pragma unroll
    for (int mf = 0; mf < 4; ++mf)
#pragma unroll
      for (int nf = 0; nf < 2; ++nf) {
        f32x4 v = acc[mf][nf];
        int s = rowbase + wm * 64 + mf * 16 + l15;
        int c = cb + wn * 32 + nf * 16 + g * 4;
        int b = s >> 11, s2 = s & 2047, hd = c >> 6, h = c & 63;
        uint2 w; w.x = cvtpk(v[0], v[1]); w.y = cvtpk(v[2], v[3]);
        *reinterpret_cast<uint2*>(dst + ((size_t)(b * 16 + hd) * 2048 + s2) * 64 + h) = w;
      }
  } else {  // C: lane col h = l15-based, reg quad = 4 s-rows -> V^T contiguous in s
    const int cb = colbase - 2048;
#pragma unroll
    for (int mf = 0; mf < 4; ++mf)
#pragma unroll
      for (int nf = 0; nf < 2; ++nf) {
        f32x4 v = acc[mf][nf];
        int s = rowbase + wm * 64 + mf * 16 + g * 4;
        int c = cb + wn * 32 + nf * 16 + l15;
        int b = s >> 11, s2 = s & 2047, hd = c >> 6, h = c & 63;
        uint2 w; w.x = cvtpk(v[0], v[1]); w.y = cvtpk(v[2], v[3]);
        *reinterpret_cast<uint2*>(dv + ((size_t)(b * 16 + hd) * 64 + h) * 2048 + s2) = w;
      }
  }
}

// ------------- out-projection GEMM: BM=128, BN=64, BK=64, dbuf -------------
// C^T via MFMA(b,a); f32x4 store to row-major [4096][1024]. Grid 16x32 = 512 blocks.
__global__ __launch_bounds__(256)
void k_gemmo(const unsigned short* __restrict__ A, const unsigned short* __restrict__ W,
             float* __restrict__ df) {
  __shared__ __align__(16) unsigned short Al[2][8192];  // 128 x 64
  __shared__ __align__(16) unsigned short Bl[2][4096];  // 64 x 64
  const int tid = threadIdx.x;
  const int lane = tid & 63, wid = tid >> 6;
  const int g = lane >> 4, l15 = lane & 15, l7 = l15 & 7;
  const int wm = wid >> 1, wn = wid & 1;
  const int rowbase = blockIdx.y * 128;
  const int colbase = blockIdx.x * 64;
  const int xgl = (g ^ l7) << 4;

  const int jr = tid >> 3;
  const int sc = ((tid & 7) ^ (jr & 7)) << 3;
  const unsigned short* As0 = A + (size_t)(rowbase + jr) * 1024 + sc;
  const unsigned short* Ws0 = W + (size_t)(colbase + jr) * 1024 + sc;

  const f32x4 zf = {0.f, 0.f, 0.f, 0.f};
  f32x4 acc[4][2];
#pragma unroll
  for (int mf = 0; mf < 4; ++mf) { acc[mf][0] = zf; acc[mf][1] = zf; }

  auto stage = [&](int buf, int k0) {
    char* Ad = (char*)&Al[buf][0];
    char* Bd = (char*)&Bl[buf][0];
#pragma unroll
    for (int p = 0; p < 4; ++p)
      __builtin_amdgcn_global_load_lds((gp_t)(As0 + (size_t)p * 32 * 1024 + k0),
                                       (lp_t)(Ad + (p * 256 + tid) * 16), 16, 0, 0);
#pragma unroll
    for (int p = 0; p < 2; ++p)
      __builtin_amdgcn_global_load_lds((gp_t)(Ws0 + (size_t)p * 32 * 1024 + k0),
                                       (lp_t)(Bd + (p * 256 + tid) * 16), 16, 0, 0);
  };

  stage(0, 0);
  __syncthreads();
#pragma unroll 1
  for (int s = 0; s < 16; ++s) {
    if (s < 15) stage((s + 1) & 1, (s + 1) * 64);
    const char* Ac = (const char*)&Al[s & 1][0];
    const char* Bc = (const char*)&Bl[s & 1][0];
    __builtin_amdgcn_s_setprio(1);
#pragma unroll
    for (int kk = 0; kk < 2; ++kk) {
      short8v af[4], bfr[2];
#pragma unroll
      for (int mf = 0; mf < 4; ++mf)
        af[mf] = *reinterpret_cast<const short8v*>(
            Ac + ((wm * 64 + mf * 16 + l15) << 7) + (xgl ^ (kk << 6)));
#pragma unroll
      for (int nf = 0; nf < 2; ++nf)
        bfr[nf] = *reinterpret_cast<const short8v*>(
            Bc + ((wn * 32 + nf * 16 + l15) << 7) + (xgl ^ (kk << 6)));
#pragma unroll
      for (int mf = 0; mf < 4; ++mf)
#pragma unroll
        for (int nf = 0; nf < 2; ++nf) acc[mf][nf] = MFMA(bfr[nf], af[mf], acc[mf][nf]);
    }
    __builtin_amdgcn_s_setprio(0);
    __syncthreads();
  }

#pragma unroll
  for (int mf = 0; mf < 4; ++mf)
#pragma unroll
    for (int nf = 0; nf < 2; ++nf) {
      int s = rowbase + wm * 64 + mf * 16 + l15;
      int c = colbase + wn * 32 + nf * 16 + g * 4;
      *reinterpret_cast<f32x4*>(df + (size_t)s * 1024 + c) = acc[mf][nf];
    }
}

// ---------------- flash attention: two-chunk phases + bf16 bias (R16 best) ----------------
// block = (f-tile 128, one (b,head)); 4 waves x 2 rowgroups x 16 f. Grid 512 (2 blocks/CU).
__global__ __launch_bounds__(256, 2)
void k_attn(const unsigned short* __restrict__ qw,    // [B*N][F][64] (* scale * log2e)
            const unsigned short* __restrict__ kw,    // [B*N][T][64]
            const unsigned short* __restrict__ vtw,   // [B*N][64][T]
            const u32* __restrict__ biaspu,           // packed bf16 C-frag layout (* log2e)
            unsigned short* __restrict__ attnb) {     // [B][F][N*64] bf16
  __shared__ __align__(16) unsigned short Kl[2][2][4096];  // [pairbuf][sub][64x64]
  __shared__ __align__(16) unsigned short Vl[2][2][4096];
  __shared__ __align__(16) unsigned short Pl[4][2048];     // per wave: 2 rg x 16f x 64t

  const int tid = threadIdx.x;
  const int lane = tid & 63, wid = tid >> 6;
  const int g = lane >> 4, l15 = lane & 15, l7 = l15 & 7;
  const int xgl = (g ^ l7) << 4;

  const int bid = blockIdx.x;  // ft-major: 32 consecutive blocks share a bias slab
  const int ft = bid >> 5, bn = bid & 31;
  const int b = bn >> 4, n = bn & 15;

  const size_t hoff = (size_t)bn * (2048 * 64);
  const unsigned short* qp = qw + hoff;
  const unsigned short* kp = kw + hoff;
  const unsigned short* vp = vtw + hoff;

  const int f0 = ft * 128 + wid * 32;   // wave's 32 f-rows (2 rowgroups of 16)
  const int fbb = ft * 8 + wid * 2;     // bias 16-row block index for rg=0

  // staging sources (pre-swizzled)
  const int jr = tid >> 3;
  const int sc = ((tid & 7) ^ (jr & 7)) << 3;
  const unsigned short* Ks0 = kp + jr * 64 + sc;
  const unsigned short* Ks1 = kp + (jr + 32) * 64 + sc;
  const unsigned short* Vs0 = vp + jr * 2048 + sc;
  const unsigned short* Vs1 = vp + (jr + 32) * 2048 + sc;

  auto stage_pair = [&](int pb, int pi) {  // stages chunks 2pi, 2pi+1 (8 VMEM/thread)
#pragma unroll
    for (int s = 0; s < 2; ++s) {
      int ci = 2 * pi + s;
      char* Kd = (char*)&Kl[pb][s][0];
      char* Vd = (char*)&Vl[pb][s][0];
      int ko = ci << 12, vo = ci << 6;
      __builtin_amdgcn_global_load_lds((gp_t)(Ks0 + ko), (lp_t)(Kd + tid * 16), 16, 0, 0);
      __builtin_amdgcn_global_load_lds((gp_t)(Ks1 + ko), (lp_t)(Kd + 4096 + tid * 16), 16, 0, 0);
      __builtin_amdgcn_global_load_lds((gp_t)(Vs0 + vo), (lp_t)(Vd + tid * 16), 16, 0, 0);
      __builtin_amdgcn_global_load_lds((gp_t)(Vs1 + vo), (lp_t)(Vd + 4096 + tid * 16), 16, 0, 0);
    }
  };

  // Q as B-fragment per rowgroup (col f = f0 + rg*16 + l15)
  short8v aq[2][2];
#pragma unroll
  for (int rg = 0; rg < 2; ++rg) {
    aq[rg][0] = *reinterpret_cast<const short8v*>(
        &qp[(size_t)(f0 + rg * 16 + l15) * 64 + g * 8]);
    aq[rg][1] = *reinterpret_cast<const short8v*>(
        &qp[(size_t)(f0 + rg * 16 + l15) * 64 + 32 + g * 8]);
  }

  // bias u32 address: ((fb*32+ci)*2 + tp)*256 + lane*4  (fb = fbb + rg)
  const u32* bias_lane = biaspu + (size_t)fbb * 16384 + lane * 4;

  const f32x4 zf = {0.f, 0.f, 0.f, 0.f};
  f32x4 o[2][4];
#pragma unroll
  for (int rg = 0; rg < 2; ++rg)
#pragma unroll
    for (int ht = 0; ht < 4; ++ht) o[rg][ht] = zf;
  float ls0 = 0.f, ls1 = 0.f;
  char* Pb = (char*)&Pl[wid][0] + l15 * 128;  // rg adds +2048 bytes

  auto bload = [&](int ci, u32x4 bc[2][2]) {  // 4 VMEM (16B) per chunk
#pragma unroll
    for (int rg = 0; rg < 2; ++rg)
#pragma unroll
      for (int tp = 0; tp < 2; ++tp)
        bc[rg][tp] = *reinterpret_cast<const u32x4*>(
            bias_lane + (size_t)rg * 16384 + ci * 512 + tp * 256);
  };

  auto qk = [&](const char* Kc, const u32x4 bc[2][2], f32x4 st[2][4]) {
    __builtin_amdgcn_s_setprio(1);
#pragma unroll
    for (int tt = 0; tt < 4; ++tt) {
      short8v kb0 = *reinterpret_cast<const short8v*>(Kc + ((tt * 16 + l15) << 7) + xgl);
      short8v kb1 = *reinterpret_cast<const short8v*>(Kc + ((tt * 16 + l15) << 7) + (xgl ^ 64));
#pragma unroll
      for (int rg = 0; rg < 2; ++rg) {
        u32 w0 = bc[rg][tt >> 1][(tt & 1) * 2];
        u32 w1 = bc[rg][tt >> 1][(tt & 1) * 2 + 1];
        f32x4 bcr;
        bcr[0] = __uint_as_float(w0 << 16);
        bcr[1] = __uint_as_float(w0 & 0xFFFF0000u);
        bcr[2] = __uint_as_float(w1 << 16);
        bcr[3] = __uint_as_float(w1 & 0xFFFF0000u);
        st[rg][tt] = MFMA(kb1, aq[rg][1], MFMA(kb0, aq[rg][0], bcr));
      }
    }
    __builtin_amdgcn_s_setprio(0);
  };

  auto sm = [&](const f32x4 st[2][4]) {  // fixed-max softmax; P -> LDS
#pragma unroll
    for (int rg = 0; rg < 2; ++rg) {
      float rs = 0.f;
#pragma unroll
      for (int tt = 0; tt < 4; ++tt) {
        float p0 = __builtin_amdgcn_exp2f(st[rg][tt][0]);
        float p1 = __builtin_amdgcn_exp2f(st[rg][tt][1]);
        float p2 = __builtin_amdgcn_exp2f(st[rg][tt][2]);
        float p3 = __builtin_amdgcn_exp2f(st[rg][tt][3]);
        rs += (p0 + p1) + (p2 + p3);
        uint2 w;
        w.x = cvtpk(p0, p1);
        w.y = cvtpk(p2, p3);
        *reinterpret_cast<uint2*>(Pb + rg * 2048 + ((tt * 32 + g * 8) ^ (l7 * 16))) = w;
      }
      rs += __shfl_xor(rs, 16);
      rs += __shfl_xor(rs, 32);
      if (rg == 0) ls0 += rs; else ls1 += rs;
    }
  };

  auto pv = [&](const char* Vc) {
    __builtin_amdgcn_s_setprio(1);
#pragma unroll
    for (int c = 0; c < 2; ++c) {
      short8v pa0 = *reinterpret_cast<const short8v*>(Pb + ((c << 6) ^ xgl));
      short8v pa1 = *reinterpret_cast<const short8v*>(Pb + 2048 + ((c << 6) ^ xgl));
#pragma unroll
      for (int ht = 0; ht < 4; ++ht) {
        short8v vb = *reinterpret_cast<const short8v*>(
            Vc + ((ht * 16 + l15) << 7) + (xgl ^ (c << 6)));
        o[0][ht] = MFMA(pa0, vb, o[0][ht]);
        o[1][ht] = MFMA(pa1, vb, o[1][ht]);
      }
    }
    __builtin_amdgcn_s_setprio(0);
  };

  u32x4 cbA[2][2], cbB[2][2], nbA[2][2], nbB[2][2];
  stage_pair(0, 0);
  bload(0, cbA);
  bload(1, cbB);
  __syncthreads();

#pragma unroll 1
  for (int ph = 0; ph < 16; ++ph) {
    const int pb = ph & 1;
    if (ph < 15) stage_pair(pb ^ 1, ph + 1);
    const char* K0 = (const char*)&Kl[pb][0][0];
    const char* K1 = (const char*)&Kl[pb][1][0];
    const char* V0 = (const char*)&Vl[pb][0][0];
    const char* V1 = (const char*)&Vl[pb][1][0];

    f32x4 stA[2][4], stB[2][4];
    qk(K0, cbA, stA);            // MFMA chunk A
    if (ph < 15) bload(2 * ph + 2, nbA);
    qk(K1, cbB, stB);            // MFMA chunk B fills A's latency
    if (ph < 15) bload(2 * ph + 3, nbB);
    sm(stA);                     // VALU + P_A store
    pv(V0);                      // MFMA reads P_A; stB's exp2 can overlap here
    sm(stB);                     // P_B store
    pv(V1);                      // MFMA chunk B

    __syncthreads();
#pragma unroll
    for (int rg = 0; rg < 2; ++rg)
#pragma unroll
      for (int q = 0; q < 2; ++q) { cbA[rg][q] = nbA[rg][q]; cbB[rg][q] = nbB[rg][q]; }
  }

#pragma unroll
  for (int rg = 0; rg < 2; ++rg) {
    float inv = 1.f / (rg == 0 ? ls0 : ls1);
    float i0 = __shfl(inv, g * 4 + 0, 16);
    float i1 = __shfl(inv, g * 4 + 1, 16);
    float i2 = __shfl(inv, g * 4 + 2, 16);
    float i3 = __shfl(inv, g * 4 + 3, 16);
#pragma unroll
    for (int ht = 0; ht < 4; ++ht) {
      unsigned short* ob = &attnb[((size_t)b * 2048 + f0 + rg * 16 + g * 4) * 1024 +
                                  n * 64 + ht * 16 + l15];
      ob[0] = f2bf(o[rg][ht][0] * i0);
      ob[1024] = f2bf(o[rg][ht][1] * i1);
      ob[2048] = f2bf(o[rg][ht][2] * i2);
      ob[3072] = f2bf(o[rg][ht][3] * i3);
    }
  }
}

extern "C" void kernel_launch(void* const* d_in, const int* in_sizes, int n_in,
                              void* d_out, int out_size, void* d_ws, size_t ws_size,
                              hipStream_t stream) {
  const float* query  = (const float*)d_in[0];
  const float* source = (const float*)d_in[1];
  const float* bias   = (const float*)d_in[2];
  const float* wq     = (const float*)d_in[3];
  const float* wk     = (const float*)d_in[4];
  const float* wv     = (const float*)d_in[5];
  const float* wo     = (const float*)d_in[6];

  char* ws = (char*)d_ws;
  unsigned short* qin_b  = (unsigned short*)(ws + 0);         // [4096][1024] bf16
  unsigned short* src_b  = (unsigned short*)(ws + 8388608);   // [4096][1024]
  u32*            bias_u = (u32*)(ws + 0);                    // packed bf16 8MB, ALIASES qin
                                                              // (written after QKV GEMM)
  unsigned short* wqkvT  = (unsigned short*)(ws + 16777216);  // [3072][1024] wq|wk|wv
  unsigned short* woT    = (unsigned short*)(ws + 23068672);  // [1024][1024]
  unsigned short* q_ws   = (unsigned short*)(ws + 25165824);  // [32][2048][64]
  unsigned short* k_ws   = (unsigned short*)(ws + 33554432);  // [32][2048][64]
  unsigned short* vT_ws  = (unsigned short*)(ws + 41943040);  // [32][64][2048]
  unsigned short* attn_b = (unsigned short*)(ws + 50331648);  // [4096][1024]

  k_prep<<<6144, 256, 0, stream>>>(query, source, qin_b, src_b,
                                   wq, wk, wv, wo, wqkvT, woT);
  k_gemmqkv<<<dim3(48, 32), 256, 0, stream>>>(qin_b, src_b, wqkvT, q_ws, k_ws, vT_ws);
  k_bias_perm<<<4096, 256, 0, stream>>>(bias, bias_u);  // reuses [0,8MB) after QKV GEMM
  k_attn<<<512, 256, 0, stream>>>(q_ws, k_ws, vT_ws, bias_u, attn_b);
  k_gemmo<<<dim3(16, 32), 256, 0, stream>>>(attn_b, woT, (float*)d_out);
}

// Round 19
// 130.022 us; speedup vs baseline: 1.2206x; 1.0262x over previous
//
#include <hip/hip_runtime.h>

// Shapes: B=2, F=T=2048, HIDDEN=1024, HEADS=16, DEPTH=64
#define LOG2E 1.44269504f

typedef __attribute__((ext_vector_type(8))) short short8v;   // 8 bf16
typedef __attribute__((ext_vector_type(4))) float f32x4;
typedef unsigned int u32;
typedef __attribute__((ext_vector_type(4))) u32 u32x4;
typedef __attribute__((address_space(1))) const u32* gp_t;
typedef __attribute__((address_space(3))) u32* lp_t;

#define MFMA(a, b, c) __builtin_amdgcn_mfma_f32_16x16x32_bf16((a), (b), (c), 0, 0, 0)

__device__ __forceinline__ unsigned short f2bf(float f) {  // RNE fp32->bf16
  unsigned int u = __float_as_uint(f);
  u = (u + 0x7fffu + ((u >> 16) & 1u)) >> 16;
  return (unsigned short)u;
}
__device__ __forceinline__ u32 cvtpk(float lo, float hi) {  // HW RNE pack (T12)
  u32 r;
  asm("v_cvt_pk_bf16_f32 %0, %1, %2" : "=v"(r) : "v"(lo), "v"(hi));
  return r;
}

// ------ fused prep: input cvt (blocks 0..2047) + weight transpose (2048..6143)
//        + optional bias permute (6144..10239, only when bias_u doesn't alias inputs) ------
__global__ __launch_bounds__(256)
void k_prep(const float* __restrict__ query, const float* __restrict__ source,
            unsigned short* __restrict__ qin_b, unsigned short* __restrict__ src_b,
            const float* __restrict__ w0, const float* __restrict__ w1,
            const float* __restrict__ w2, const float* __restrict__ w3,
            unsigned short* __restrict__ wqkvT, unsigned short* __restrict__ woT,
            const float* __restrict__ biasf, u32* __restrict__ bias_u) {
  __shared__ float tile[32][33];
  const int bid = blockIdx.x;
  const int tid = threadIdx.x;
  if (bid < 2048) {
    const int n4each = 1048576;
    for (int i = bid * 256 + tid; i < 2 * n4each; i += 2048 * 256) {
      bool second = i >= n4each;
      int j = second ? i - n4each : i;
      float4 v = second ? reinterpret_cast<const float4*>(source)[j]
                        : reinterpret_cast<const float4*>(query)[j];
      ushort4 o;
      o.x = f2bf(v.x); o.y = f2bf(v.y); o.z = f2bf(v.z); o.w = f2bf(v.w);
      (second ? reinterpret_cast<ushort4*>(src_b) : reinterpret_cast<ushort4*>(qin_b))[j] = o;
    }
  } else if (bid < 6144) {
    const int t = bid - 2048;
    const int z = t >> 10, rem = t & 1023;
    const float* in = (z == 0) ? w0 : (z == 1) ? w1 : (z == 2) ? w2 : w3;
    unsigned short* out = (z < 3) ? (wqkvT + (size_t)z * 1048576) : woT;
    const float scale = (z == 0) ? 0.125f * LOG2E : 1.0f;
    const int bx = (rem & 31) * 32, by = (rem >> 5) * 32;
    const int tx = tid & 31, ty = tid >> 5;  // (32,8)
    for (int r = ty; r < 32; r += 8)
      tile[r][tx] = in[(size_t)(by + r) * 1024 + bx + tx];
    __syncthreads();
    for (int r = ty; r < 32; r += 8)
      out[(size_t)(bx + r) * 1024 + by + tx] = f2bf(tile[tx][r] * scale);
  } else {
    // bias permute to packed bf16 C-frag layout (*LOG2E)
    const int pb = bid - 6144;  // fb*32 + ch, 0..4095
    const int fb = pb >> 5, ch = pb & 31;
    const int tt = tid >> 6, rem = tid & 63;
    const int g = rem >> 4, l15 = rem & 15;
    float4 v = *reinterpret_cast<const float4*>(
        &biasf[(size_t)(fb * 16 + l15) * 2048 + ch * 64 + tt * 16 + g * 4]);
    uint2 w;
    w.x = cvtpk(v.x * LOG2E, v.y * LOG2E);
    w.y = cvtpk(v.z * LOG2E, v.w * LOG2E);
    *reinterpret_cast<uint2*>(
        &bias_u[((size_t)(pb * 2 + (tt >> 1)) * 64 + rem) * 4 + (tt & 1) * 2]) = w;
  }
}

// ---- standalone bias permute (fallback when bias_u must alias qin_b) ----
__global__ void k_bias_perm(const float* __restrict__ in, u32* __restrict__ out) {
  int bid = blockIdx.x;  // fb*32 + ch, grid 4096
  int fb = bid >> 5, ch = bid & 31;
  int tid = threadIdx.x;
  int tt = tid >> 6, rem = tid & 63;
  int g = rem >> 4, l15 = rem & 15;
  float4 v = *reinterpret_cast<const float4*>(
      &in[(size_t)(fb * 16 + l15) * 2048 + ch * 64 + tt * 16 + g * 4]);
  uint2 w;
  w.x = cvtpk(v.x * LOG2E, v.y * LOG2E);
  w.y = cvtpk(v.z * LOG2E, v.w * LOG2E);
  *reinterpret_cast<uint2*>(&out[((size_t)(bid * 2 + (tt >> 1)) * 64 + rem) * 4 + (tt & 1) * 2]) = w;
}

// ------------- fused QKV projection GEMM: BM=128, BN=64, BK=64, dbuf (R13-best) -------------
// N=3072 (wq|wk|wv concat). Grid 48x32 = 1536 blocks; 48KB LDS -> 3 blocks/CU resident.
// Q/K blocks (colbase<2048): C^T via MFMA(b,a), quad on h -> uint2 store to [bh][s][64].
// V blocks: MFMA(a,b), quad on s -> uint2 store to V^T [bh][h][2048].
__global__ __launch_bounds__(256)
void k_gemmqkv(const unsigned short* __restrict__ Aq, const unsigned short* __restrict__ Asrc,
               const unsigned short* __restrict__ W,
               unsigned short* __restrict__ dq, unsigned short* __restrict__ dk,
               unsigned short* __restrict__ dv) {
  __shared__ __align__(16) unsigned short Al[2][8192];  // 128 x 64
  __shared__ __align__(16) unsigned short Bl[2][4096];  // 64 x 64
  const int tid = threadIdx.x;
  const int lane = tid & 63, wid = tid >> 6;
  const int g = lane >> 4, l15 = lane & 15, l7 = l15 & 7;
  const int wm = wid >> 1, wn = wid & 1;
  const int rowbase = blockIdx.y * 128;
  const int colbase = blockIdx.x * 64;  // 0..3008
  const bool isV = colbase >= 2048;
  const unsigned short* A = (colbase < 1024) ? Aq : Asrc;
  const int xgl = (g ^ l7) << 4;

  const int jr = tid >> 3;
  const int sc = ((tid & 7) ^ (jr & 7)) << 3;
  const unsigned short* As0 = A + (size_t)(rowbase + jr) * 1024 + sc;
  const unsigned short* Ws0 = W + (size_t)(colbase + jr) * 1024 + sc;

  const f32x4 zf = {0.f, 0.f, 0.f, 0.f};
  f32x4 acc[4][2];
#pragma unroll
  for (int mf = 0; mf < 4; ++mf) { acc[mf][0] = zf; acc[mf][1] = zf; }

  auto stage = [&](int buf, int k0) {
    char* Ad = (char*)&Al[buf][0];
    char* Bd = (char*)&Bl[buf][0];
#pragma unroll
    for (int p = 0; p < 4; ++p)
      __builtin_amdgcn_global_load_lds((gp_t)(As0 + (size_t)p * 32 * 1024 + k0),
                                       (lp_t)(Ad + (p * 256 + tid) * 16), 16, 0, 0);
#pragma unroll
    for (int p = 0; p < 2; ++p)
      __builtin_amdgcn_global_load_lds((gp_t)(Ws0 + (size_t)p * 32 * 1024 + k0),
                                       (lp_t)(Bd + (p * 256 + tid) * 16), 16, 0, 0);
  };
  auto ldfrags = [&](int buf, int kk, short8v af[4], short8v bfr[2]) {
    const char* Ac = (const char*)&Al[buf][0];
    const char* Bc = (const char*)&Bl[buf][0];
#pragma unroll
    for (int mf = 0; mf < 4; ++mf)
      af[mf] = *reinterpret_cast<const short8v*>(
          Ac + ((wm * 64 + mf * 16 + l15) << 7) + (xgl ^ (kk << 6)));
#pragma unroll
    for (int nf = 0; nf < 2; ++nf)
      bfr[nf] = *reinterpret_cast<const short8v*>(
          Bc + ((wn * 32 + nf * 16 + l15) << 7) + (xgl ^ (kk << 6)));
  };

  stage(0, 0);
  __syncthreads();
#pragma unroll 1
  for (int s = 0; s < 16; ++s) {
    if (s < 15) stage((s + 1) & 1, (s + 1) * 64);
    __builtin_amdgcn_s_setprio(1);
    if (!isV) {
#pragma unroll
      for (int kk = 0; kk < 2; ++kk) {
        short8v af[4], bfr[2];
        ldfrags(s & 1, kk, af, bfr);
#pragma unroll
        for (int mf = 0; mf < 4; ++mf)
#pragma unroll
          for (int nf = 0; nf < 2; ++nf) acc[mf][nf] = MFMA(bfr[nf], af[mf], acc[mf][nf]);
      }
    } else {
#pragma unroll
      for (int kk = 0; kk < 2; ++kk) {
        short8v af[4], bfr[2];
        ldfrags(s & 1, kk, af, bfr);
#pragma unroll
        for (int mf = 0; mf < 4; ++mf)
#pragma unroll
          for (int nf = 0; nf < 2; ++nf) acc[mf][nf] = MFMA(af[mf], bfr[nf], acc[mf][nf]);
      }
    }
    __builtin_amdgcn_s_setprio(0);
    __syncthreads();
  }

  if (!isV) {  // C^T: lane row s = l15-based, reg quad = 4 h-cols
    unsigned short* dst = (colbase < 1024) ? dq : dk;
    const int cb = colbase & 1023;
#pragma unroll
    for (int mf = 0; mf < 4; ++mf)
#pragma unroll
      for (int nf = 0; nf < 2; ++nf) {
        f32x4 v = acc[mf][nf];
        int s = rowbase + wm * 64 + mf * 16 + l15;
        int c = cb + wn * 32 + nf * 16 + g * 4;
        int b = s >> 11, s2 = s & 2047, hd = c >> 6, h = c & 63;
        uint2 w; w.x = cvtpk(v[0], v[1]); w.y = cvtpk(v[2], v[3]);
        *reinterpret_cast<uint2*>(dst + ((size_t)(b * 16 + hd) * 2048 + s2) * 64 + h) = w;
      }
  } else {  // C: lane col h = l15-based, reg quad = 4 s-rows -> V^T contiguous in s
    const int cb = colbase - 2048;
#pragma unroll
    for (int mf = 0; mf < 4; ++mf)
#pragma unroll
      for (int nf = 0; nf < 2; ++nf) {
        f32x4 v = acc[mf][nf];
        int s = rowbase + wm * 64 + mf * 16 + g * 4;
        int c = cb + wn * 32 + nf * 16 + l15;
        int b = s >> 11, s2 = s & 2047, hd = c >> 6, h = c & 63;
        uint2 w; w.x = cvtpk(v[0], v[1]); w.y = cvtpk(v[2], v[3]);
        *reinterpret_cast<uint2*>(dv + ((size_t)(b * 16 + hd) * 64 + h) * 2048 + s2) = w;
      }
  }
}

// ------------- out-projection GEMM: BM=128, BN=64, BK=64, dbuf -------------
// C^T via MFMA(b,a); f32x4 store to row-major [4096][1024]. Grid 16x32 = 512 blocks.
__global__ __launch_bounds__(256)
void k_gemmo(const unsigned short* __restrict__ A, const unsigned short* __restrict__ W,
             float* __restrict__ df) {
  __shared__ __align__(16) unsigned short Al[2][8192];  // 128 x 64
  __shared__ __align__(16) unsigned short Bl[2][4096];  // 64 x 64
  const int tid = threadIdx.x;
  const int lane = tid & 63, wid = tid >> 6;
  const int g = lane >> 4, l15 = lane & 15, l7 = l15 & 7;
  const int wm = wid >> 1, wn = wid & 1;
  const int rowbase = blockIdx.y * 128;
  const int colbase = blockIdx.x * 64;
  const int xgl = (g ^ l7) << 4;

  const int jr = tid >> 3;
  const int sc = ((tid & 7) ^ (jr & 7)) << 3;
  const unsigned short* As0 = A + (size_t)(rowbase + jr) * 1024 + sc;
  const unsigned short* Ws0 = W + (size_t)(colbase + jr) * 1024 + sc;

  const f32x4 zf = {0.f, 0.f, 0.f, 0.f};
  f32x4 acc[4][2];
#pragma unroll
  for (int mf = 0; mf < 4; ++mf) { acc[mf][0] = zf; acc[mf][1] = zf; }

  auto stage = [&](int buf, int k0) {
    char* Ad = (char*)&Al[buf][0];
    char* Bd = (char*)&Bl[buf][0];
#pragma unroll
    for (int p = 0; p < 4; ++p)
      __builtin_amdgcn_global_load_lds((gp_t)(As0 + (size_t)p * 32 * 1024 + k0),
                                       (lp_t)(Ad + (p * 256 + tid) * 16), 16, 0, 0);
#pragma unroll
    for (int p = 0; p < 2; ++p)
      __builtin_amdgcn_global_load_lds((gp_t)(Ws0 + (size_t)p * 32 * 1024 + k0),
                                       (lp_t)(Bd + (p * 256 + tid) * 16), 16, 0, 0);
  };

  stage(0, 0);
  __syncthreads();
#pragma unroll 1
  for (int s = 0; s < 16; ++s) {
    if (s < 15) stage((s + 1) & 1, (s + 1) * 64);
    const char* Ac = (const char*)&Al[s & 1][0];
    const char* Bc = (const char*)&Bl[s & 1][0];
    __builtin_amdgcn_s_setprio(1);
#pragma unroll
    for (int kk = 0; kk < 2; ++kk) {
      short8v af[4], bfr[2];
#pragma unroll
      for (int mf = 0; mf < 4; ++mf)
        af[mf] = *reinterpret_cast<const short8v*>(
            Ac + ((wm * 64 + mf * 16 + l15) << 7) + (xgl ^ (kk << 6)));
#pragma unroll
      for (int nf = 0; nf < 2; ++nf)
        bfr[nf] = *reinterpret_cast<const short8v*>(
            Bc + ((wn * 32 + nf * 16 + l15) << 7) + (xgl ^ (kk << 6)));
#pragma unroll
      for (int mf = 0; mf < 4; ++mf)
#pragma unroll
        for (int nf = 0; nf < 2; ++nf) acc[mf][nf] = MFMA(bfr[nf], af[mf], acc[mf][nf]);
    }
    __builtin_amdgcn_s_setprio(0);
    __syncthreads();
  }

#pragma unroll
  for (int mf = 0; mf < 4; ++mf)
#pragma unroll
    for (int nf = 0; nf < 2; ++nf) {
      int s = rowbase + wm * 64 + mf * 16 + l15;
      int c = colbase + wn * 32 + nf * 16 + g * 4;
      *reinterpret_cast<f32x4*>(df + (size_t)s * 1024 + c) = acc[mf][nf];
    }
}

// ---------------- flash attention: two-chunk phases + bf16 bias (R16 best) ----------------
// block = (f-tile 128, one (b,head)); 4 waves x 2 rowgroups x 16 f. Grid 512 (2 blocks/CU).
__global__ __launch_bounds__(256, 2)
void k_attn(const unsigned short* __restrict__ qw,    // [B*N][F][64] (* scale * log2e)
            const unsigned short* __restrict__ kw,    // [B*N][T][64]
            const unsigned short* __restrict__ vtw,   // [B*N][64][T]
            const u32* __restrict__ biaspu,           // packed bf16 C-frag layout (* log2e)
            unsigned short* __restrict__ attnb) {     // [B][F][N*64] bf16
  __shared__ __align__(16) unsigned short Kl[2][2][4096];  // [pairbuf][sub][64x64]
  __shared__ __align__(16) unsigned short Vl[2][2][4096];
  __shared__ __align__(16) unsigned short Pl[4][2048];     // per wave: 2 rg x 16f x 64t

  const int tid = threadIdx.x;
  const int lane = tid & 63, wid = tid >> 6;
  const int g = lane >> 4, l15 = lane & 15, l7 = l15 & 7;
  const int xgl = (g ^ l7) << 4;

  const int bid = blockIdx.x;  // ft-major: 32 consecutive blocks share a bias slab
  const int ft = bid >> 5, bn = bid & 31;
  const int b = bn >> 4, n = bn & 15;

  const size_t hoff = (size_t)bn * (2048 * 64);
  const unsigned short* qp = qw + hoff;
  const unsigned short* kp = kw + hoff;
  const unsigned short* vp = vtw + hoff;

  const int f0 = ft * 128 + wid * 32;   // wave's 32 f-rows (2 rowgroups of 16)
  const int fbb = ft * 8 + wid * 2;     // bias 16-row block index for rg=0

  // staging sources (pre-swizzled)
  const int jr = tid >> 3;
  const int sc = ((tid & 7) ^ (jr & 7)) << 3;
  const unsigned short* Ks0 = kp + jr * 64 + sc;
  const unsigned short* Ks1 = kp + (jr + 32) * 64 + sc;
  const unsigned short* Vs0 = vp + jr * 2048 + sc;
  const unsigned short* Vs1 = vp + (jr + 32) * 2048 + sc;

  auto stage_pair = [&](int pb, int pi) {  // stages chunks 2pi, 2pi+1 (8 VMEM/thread)
#pragma unroll
    for (int s = 0; s < 2; ++s) {
      int ci = 2 * pi + s;
      char* Kd = (char*)&Kl[pb][s][0];
      char* Vd = (char*)&Vl[pb][s][0];
      int ko = ci << 12, vo = ci << 6;
      __builtin_amdgcn_global_load_lds((gp_t)(Ks0 + ko), (lp_t)(Kd + tid * 16), 16, 0, 0);
      __builtin_amdgcn_global_load_lds((gp_t)(Ks1 + ko), (lp_t)(Kd + 4096 + tid * 16), 16, 0, 0);
      __builtin_amdgcn_global_load_lds((gp_t)(Vs0 + vo), (lp_t)(Vd + tid * 16), 16, 0, 0);
      __builtin_amdgcn_global_load_lds((gp_t)(Vs1 + vo), (lp_t)(Vd + 4096 + tid * 16), 16, 0, 0);
    }
  };

  // Q as B-fragment per rowgroup (col f = f0 + rg*16 + l15)
  short8v aq[2][2];
#pragma unroll
  for (int rg = 0; rg < 2; ++rg) {
    aq[rg][0] = *reinterpret_cast<const short8v*>(
        &qp[(size_t)(f0 + rg * 16 + l15) * 64 + g * 8]);
    aq[rg][1] = *reinterpret_cast<const short8v*>(
        &qp[(size_t)(f0 + rg * 16 + l15) * 64 + 32 + g * 8]);
  }

  // bias u32 address: ((fb*32+ci)*2 + tp)*256 + lane*4  (fb = fbb + rg)
  const u32* bias_lane = biaspu + (size_t)fbb * 16384 + lane * 4;

  const f32x4 zf = {0.f, 0.f, 0.f, 0.f};
  f32x4 o[2][4];
#pragma unroll
  for (int rg = 0; rg < 2; ++rg)
#pragma unroll
    for (int ht = 0; ht < 4; ++ht) o[rg][ht] = zf;
  float ls0 = 0.f, ls1 = 0.f;
  char* Pb = (char*)&Pl[wid][0] + l15 * 128;  // rg adds +2048 bytes

  auto bload = [&](int ci, u32x4 bc[2][2]) {  // 4 VMEM (16B) per chunk
#pragma unroll
    for (int rg = 0; rg < 2; ++rg)
#pragma unroll
      for (int tp = 0; tp < 2; ++tp)
        bc[rg][tp] = *reinterpret_cast<const u32x4*>(
            bias_lane + (size_t)rg * 16384 + ci * 512 + tp * 256);
  };

  auto qk = [&](const char* Kc, const u32x4 bc[2][2], f32x4 st[2][4]) {
    __builtin_amdgcn_s_setprio(1);
#pragma unroll
    for (int tt = 0; tt < 4; ++tt) {
      short8v kb0 = *reinterpret_cast<const short8v*>(Kc + ((tt * 16 + l15) << 7) + xgl);
      short8v kb1 = *reinterpret_cast<const short8v*>(Kc + ((tt * 16 + l15) << 7) + (xgl ^ 64));
#pragma unroll
      for (int rg = 0; rg < 2; ++rg) {
        u32 w0 = bc[rg][tt >> 1][(tt & 1) * 2];
        u32 w1 = bc[rg][tt >> 1][(tt & 1) * 2 + 1];
        f32x4 bcr;
        bcr[0] = __uint_as_float(w0 << 16);
        bcr[1] = __uint_as_float(w0 & 0xFFFF0000u);
        bcr[2] = __uint_as_float(w1 << 16);
        bcr[3] = __uint_as_float(w1 & 0xFFFF0000u);
        st[rg][tt] = MFMA(kb1, aq[rg][1], MFMA(kb0, aq[rg][0], bcr));
      }
    }
    __builtin_amdgcn_s_setprio(0);
  };

  auto sm = [&](const f32x4 st[2][4]) {  // fixed-max softmax; P -> LDS
#pragma unroll
    for (int rg = 0; rg < 2; ++rg) {
      float rs = 0.f;
#pragma unroll
      for (int tt = 0; tt < 4; ++tt) {
        float p0 = __builtin_amdgcn_exp2f(st[rg][tt][0]);
        float p1 = __builtin_amdgcn_exp2f(st[rg][tt][1]);
        float p2 = __builtin_amdgcn_exp2f(st[rg][tt][2]);
        float p3 = __builtin_amdgcn_exp2f(st[rg][tt][3]);
        rs += (p0 + p1) + (p2 + p3);
        uint2 w;
        w.x = cvtpk(p0, p1);
        w.y = cvtpk(p2, p3);
        *reinterpret_cast<uint2*>(Pb + rg * 2048 + ((tt * 32 + g * 8) ^ (l7 * 16))) = w;
      }
      rs += __shfl_xor(rs, 16);
      rs += __shfl_xor(rs, 32);
      if (rg == 0) ls0 += rs; else ls1 += rs;
    }
  };

  auto pv = [&](const char* Vc) {
    __builtin_amdgcn_s_setprio(1);
#pragma unroll
    for (int c = 0; c < 2; ++c) {
      short8v pa0 = *reinterpret_cast<const short8v*>(Pb + ((c << 6) ^ xgl));
      short8v pa1 = *reinterpret_cast<const short8v*>(Pb + 2048 + ((c << 6) ^ xgl));
#pragma unroll
      for (int ht = 0; ht < 4; ++ht) {
        short8v vb = *reinterpret_cast<const short8v*>(
            Vc + ((ht * 16 + l15) << 7) + (xgl ^ (c << 6)));
        o[0][ht] = MFMA(pa0, vb, o[0][ht]);
        o[1][ht] = MFMA(pa1, vb, o[1][ht]);
      }
    }
    __builtin_amdgcn_s_setprio(0);
  };

  u32x4 cbA[2][2], cbB[2][2], nbA[2][2], nbB[2][2];
  stage_pair(0, 0);
  bload(0, cbA);
  bload(1, cbB);
  __syncthreads();

#pragma unroll 1
  for (int ph = 0; ph < 16; ++ph) {
    const int pb = ph & 1;
    if (ph < 15) stage_pair(pb ^ 1, ph + 1);
    const char* K0 = (const char*)&Kl[pb][0][0];
    const char* K1 = (const char*)&Kl[pb][1][0];
    const char* V0 = (const char*)&Vl[pb][0][0];
    const char* V1 = (const char*)&Vl[pb][1][0];

    f32x4 stA[2][4], stB[2][4];
    qk(K0, cbA, stA);            // MFMA chunk A
    if (ph < 15) bload(2 * ph + 2, nbA);
    qk(K1, cbB, stB);            // MFMA chunk B fills A's latency
    if (ph < 15) bload(2 * ph + 3, nbB);
    sm(stA);                     // VALU + P_A store
    pv(V0);                      // MFMA reads P_A; stB's exp2 can overlap here
    sm(stB);                     // P_B store
    pv(V1);                      // MFMA chunk B

    __syncthreads();
#pragma unroll
    for (int rg = 0; rg < 2; ++rg)
#pragma unroll
      for (int q = 0; q < 2; ++q) { cbA[rg][q] = nbA[rg][q]; cbB[rg][q] = nbB[rg][q]; }
  }

#pragma unroll
  for (int rg = 0; rg < 2; ++rg) {
    float inv = 1.f / (rg == 0 ? ls0 : ls1);
    float i0 = __shfl(inv, g * 4 + 0, 16);
    float i1 = __shfl(inv, g * 4 + 1, 16);
    float i2 = __shfl(inv, g * 4 + 2, 16);
    float i3 = __shfl(inv, g * 4 + 3, 16);
#pragma unroll
    for (int ht = 0; ht < 4; ++ht) {
      unsigned short* ob = &attnb[((size_t)b * 2048 + f0 + rg * 16 + g * 4) * 1024 +
                                  n * 64 + ht * 16 + l15];
      ob[0] = f2bf(o[rg][ht][0] * i0);
      ob[1024] = f2bf(o[rg][ht][1] * i1);
      ob[2048] = f2bf(o[rg][ht][2] * i2);
      ob[3072] = f2bf(o[rg][ht][3] * i3);
    }
  }
}

extern "C" void kernel_launch(void* const* d_in, const int* in_sizes, int n_in,
                              void* d_out, int out_size, void* d_ws, size_t ws_size,
                              hipStream_t stream) {
  const float* query  = (const float*)d_in[0];
  const float* source = (const float*)d_in[1];
  const float* bias   = (const float*)d_in[2];
  const float* wq     = (const float*)d_in[3];
  const float* wk     = (const float*)d_in[4];
  const float* wv     = (const float*)d_in[5];
  const float* wo     = (const float*)d_in[6];

  char* ws = (char*)d_ws;
  unsigned short* qin_b  = (unsigned short*)(ws + 0);         // [4096][1024] bf16
  unsigned short* src_b  = (unsigned short*)(ws + 8388608);   // [4096][1024]
  unsigned short* wqkvT  = (unsigned short*)(ws + 16777216);  // [3072][1024] wq|wk|wv
  unsigned short* woT    = (unsigned short*)(ws + 23068672);  // [1024][1024]
  unsigned short* q_ws   = (unsigned short*)(ws + 25165824);  // [32][2048][64]
  unsigned short* k_ws   = (unsigned short*)(ws + 33554432);  // [32][2048][64]
  unsigned short* vT_ws  = (unsigned short*)(ws + 41943040);  // [32][64][2048]
  unsigned short* attn_b = (unsigned short*)(ws + 50331648);  // [4096][1024]

  // bias_u (packed bf16, 8MB): if workspace has room past attn_b, use it and fuse the
  // permute into k_prep (removes a serial launch). Else alias [0,8MB) (dead after QKV GEMM)
  // and run the standalone permute after the QKV GEMM (R18 ordering).
  const bool roomy = ws_size >= (size_t)67108864;
  u32* bias_u = roomy ? (u32*)(ws + 58720256) : (u32*)(ws + 0);

  if (roomy) {
    k_prep<<<10240, 256, 0, stream>>>(query, source, qin_b, src_b,
                                      wq, wk, wv, wo, wqkvT, woT, bias, bias_u);
    k_gemmqkv<<<dim3(48, 32), 256, 0, stream>>>(qin_b, src_b, wqkvT, q_ws, k_ws, vT_ws);
  } else {
    k_prep<<<6144, 256, 0, stream>>>(query, source, qin_b, src_b,
                                     wq, wk, wv, wo, wqkvT, woT, bias, bias_u);
    k_gemmqkv<<<dim3(48, 32), 256, 0, stream>>>(qin_b, src_b, wqkvT, q_ws, k_ws, vT_ws);
    k_bias_perm<<<4096, 256, 0, stream>>>(bias, bias_u);
  }
  k_attn<<<512, 256, 0, stream>>>(q_ws, k_ws, vT_ws, bias_u, attn_b);
  k_gemmo<<<dim3(16, 32), 256, 0, stream>>>(attn_b, woT, (float*)d_out);
}